// Round 12
// baseline (109.614 us; speedup 1.0000x reference)
//
#include <hip/hip_runtime.h>
#include <hip/hip_bf16.h>
#include <math.h>

// GeomAttention: B=2, L=S=2048, H=8, E=D=32, fp32 in/out.
// scores = (0.5*dot - 0.5*relu(qn2*kn2 - dot^2))/sqrt(E); softmax over S; out = attn@V.
// Round 18: DMA isolation. R11 (hoisted addrs) nulled: 45.3us, all true pipe
// loads <=40%, 845 cyc/wave-tile vs ~250 of work, invariant across SIX
// structures. Every mechanism except global_load_lds itself is exonerated
// (barriers R5, conflicts 0, LDS BW R4, occupancy R10, VALU R11, reg-pipe
// R2/R7). This round: byte-identical schedule/layouts, but staging via plain
// global_load_dwordx4 -> reg -> ds_write_b128 (T14 issue-early/write-late).
// Loads for tile t+1 issue at iter top; ds_write lands after compute before
// the barrier (WAR safe by prev barrier, RAW by this one). If main <=38us,
// DMA was the hidden limiter; if 45+-2, staging is fully exonerated ->
// structural floor, declare roofline.

#define NB 2
#define NL 2048
#define NS 2048
#define NH 8
#define NBH 16
#define STRIPS 4
#define NT 16                 // 32-key tiles per 512-key strip
#define CSC 0.12751742f       // 0.5 / sqrt(32) * log2(e)
#define DEFER_THR 24.0f       // p <= 2^(24*CSC) ~= 8.4, safe in bf16

#define WS_KN2_OFF 0u
#define WS_KHKL_OFF 131072u                          // 16*2048 f32
#define WS_VT_OFF (131072u + 4194304u)               // + 16*2048*128B (K hi/lo image)
#define WS_PACC_OFF (131072u + 4194304u + 2097152u)  // + 16*64*2048B (V^T tile-major image)
#define WS_PML_OFF (WS_PACC_OFF + 16777216u)         // + 16*4*2048*32 f32
#define WS_NEED (WS_PML_OFF + 1048576u)              // + 16*4*2048*2 f32 = 24,248,320 B

typedef float f32x4 __attribute__((ext_vector_type(4)));
typedef float f32x2 __attribute__((ext_vector_type(2)));
typedef short s16x8 __attribute__((ext_vector_type(8)));
typedef unsigned short u16;

__device__ inline unsigned pk2(float a, float b) {  // bf16(a)|bf16(b)<<16, RNE
    __hip_bfloat162 t = __float22bfloat162_rn(make_float2(a, b));
    union { __hip_bfloat162 h; unsigned u; } cv;
    cv.h = t;
    return cv.u;
}
template <int CTRL>
__device__ inline float dpp_add(float x) {
    return x + __int_as_float(__builtin_amdgcn_mov_dpp(__float_as_int(x), CTRL, 0xF, 0xF, false));
}
// gfx950 cross-lane row swaps (both operands read-write)
__device__ inline void pl32(unsigned& a, unsigned& b) {
    asm("v_permlane32_swap_b32 %0, %1" : "+v"(a), "+v"(b));
}
__device__ inline void pl16(unsigned& a, unsigned& b) {
    asm("v_permlane16_swap_b32 %0, %1" : "+v"(a), "+v"(b));
}
// fallback-kernel swizzles
__device__ inline int swzK(int row) { return (row ^ (row >> 2)) & 3; }
__device__ inline int swzV(int row) { return (row + (row >> 3)) & 7; }

// ==== pre-kernel ====
// K image: [bh][key][8 chunks x 16B], phys = logical ^ (key&7); 0-3 hi, 4-7 lo.
// V image: tile-major [bh][tile(32k)][16 rows x 128B]; row r holds d={2r,2r+1},
//          slot = (d&1)*4 + (c2 ^ (r&3)), c2 = 8-key chunk within tile. kn2 fp32.
__global__ __launch_bounds__(256) void ga_pre(const float* __restrict__ K,
                                              const float* __restrict__ V,
                                              float* __restrict__ kn2w,
                                              u16* __restrict__ khkl,
                                              u16* __restrict__ vtw) {
    __shared__ float Vf[64][36];
    const int T = threadIdx.x;
    const int bh = blockIdx.x >> 5, stile = blockIdx.x & 31;
    const int b = bh >> 3, h = bh & 7;
    const int s0 = stile * 64;
    const int sk = T >> 2, kc = T & 3;

    const float* kp = K + ((size_t)((b * NS + s0 + sk) * NH + h)) * 32 + kc * 8;
    float4 f0 = *(const float4*)kp, f1 = *(const float4*)(kp + 4);
    float kx[8] = {f0.x, f0.y, f0.z, f0.w, f1.x, f1.y, f1.z, f1.w};
    unsigned hh[4], ll[4];
    float kn2p = 0.f;
#pragma unroll
    for (int i = 0; i < 4; i++) {
        float x0 = kx[2 * i], x1 = kx[2 * i + 1];
        kn2p = fmaf(x0, x0, kn2p);
        kn2p = fmaf(x1, x1, kn2p);
        unsigned h01 = pk2(x0, x1);
        hh[i] = h01;
        float h0 = __uint_as_float(h01 << 16);
        float h1 = __uint_as_float(h01 & 0xffff0000u);
        ll[i] = pk2(x0 - h0, x1 - h1);
    }
    u16* kd = khkl + ((size_t)(bh * NS + s0 + sk)) * 64;
    const int swk = sk & 7;
    *(uint4*)(kd + ((kc ^ swk) * 8)) = make_uint4(hh[0], hh[1], hh[2], hh[3]);
    *(uint4*)(kd + (((4 + kc) ^ swk) * 8)) = make_uint4(ll[0], ll[1], ll[2], ll[3]);
    kn2p = dpp_add<0xB1>(kn2p);
    kn2p = dpp_add<0x4E>(kn2p);
    if (kc == 0) kn2w[bh * NS + s0 + sk] = kn2p;

    const float* vp = V + ((size_t)((b * NS + s0 + sk) * NH + h)) * 32 + kc * 8;
    float4 g0 = *(const float4*)vp, g1 = *(const float4*)(vp + 4);
    // chunk swizzle keyed on (row>>3)&3 so the column-wise read below is <=2-way banked
    const int chv = kc ^ ((sk >> 3) & 3);
    *(float4*)&Vf[sk][chv * 8] = g0;
    *(float4*)&Vf[sk][chv * 8 + 4] = g1;
    __syncthreads();
    const int dr = T >> 3, c = T & 7;  // dr = d-row 0..31, c = 8-key chunk in 64-key stile
    float vv[8];
#pragma unroll
    for (int i = 0; i < 8; i++)
        vv[i] = Vf[c * 8 + i][(((dr >> 3) ^ (c & 3)) << 3) + (dr & 7)];
    // tile-major store: tile tt, row r = dr>>1, slot = (dr&1)*4 + ((c&3) ^ (r&3))
    const int tt = (s0 >> 5) + (c >> 2);
    const int r = dr >> 1;
    const int slot = ((dr & 1) << 2) + ((c & 3) ^ (r & 3));
    *(uint4*)(vtw + (size_t)bh * 65536 + tt * 1024 + r * 64 + slot * 8) =
        make_uint4(pk2(vv[0], vv[1]), pk2(vv[2], vv[3]), pk2(vv[4], vv[5]), pk2(vv[6], vv[7]));
}

// ==== main kernel: reg-staged (NO global_load_lds), otherwise == R11 ====
__global__ __launch_bounds__(256, 8) void ga_lean(
    const float* __restrict__ Q, const float* __restrict__ kn2w,
    const u16* __restrict__ khkl, const u16* __restrict__ vtw,
    float* __restrict__ pacc, float* __restrict__ pml) {
    __shared__ u16 sK[2][32][64];  // [buf][key][8 phys chunks x 8 u16]  8 KB
    __shared__ u16 sV[2][16][64];  // [buf][row=d>>1][8 slots x 8 u16]   4 KB

    const int T = threadIdx.x;
    const int lane = T & 63, wave = T >> 6;
    const int g = lane >> 4, lc = lane & 15, g8 = g * 8;
    // XCD grouping: same (bh,strip) group's 32 qt-blocks are 64 apart -> same XCD.
    const int blk = blockIdx.x;
    const int qt = blk >> 6, grp = blk & 63;  // grid 2048: qt 0..31
    const int bh = grp >> 2, strip = grp & 3;
    const int b = bh >> 3, h = bh & 7;
    const int qw = qt * 64 + wave * 16;
    const int kb0 = strip * 512;

    // ---- Q fragment (hi/lo bf16) + exact qn2 ----
    const float* qrow = Q + ((size_t)((b * NL + qw + lc) * NH + h)) * 32 + g8;
    float4 qa = *(const float4*)qrow, qb = *(const float4*)(qrow + 4);
    float q8[8] = {qa.x, qa.y, qa.z, qa.w, qb.x, qb.y, qb.z, qb.w};
    union { unsigned u4[4]; s16x8 v; } qh_, ql_;
    float qn2 = 0.f;
#pragma unroll
    for (int i = 0; i < 4; i++) {
        float x0 = q8[2 * i], x1 = q8[2 * i + 1];
        qn2 = fmaf(x0, x0, qn2);
        qn2 = fmaf(x1, x1, qn2);
        unsigned h01 = pk2(x0, x1);
        qh_.u4[i] = h01;
        float h0 = __uint_as_float(h01 << 16);
        float h1 = __uint_as_float(h01 & 0xffff0000u);
        ql_.u4[i] = pk2(x0 - h0, x1 - h1);
    }
    const s16x8 qh = qh_.v, ql = ql_.v;
    qn2 += __shfl_xor(qn2, 16);
    qn2 += __shfl_xor(qn2, 32);

    // ---- staging sources (contiguous 1KB per wave-load) ----
    const char* ksrc = (const char*)khkl + ((size_t)(bh * NS + kb0 + 8 * wave)) * 128 + lane * 16;
    const char* vsrc = (const char*)vtw + ((size_t)bh * 65536 + (kb0 >> 5) * 1024) * 2 +
                       wave * 1024 + lane * 16;
    const float* knt = kn2w + (size_t)bh * NS + kb0 + 4 * g;

    // ---- LDS write targets (linear, same image the DMA used to write) ----
    u16* pKw = &sK[0][8 * wave + (lane >> 3)][(lane & 7) * 8];
    u16* pVw = &sV[0][8 * wave + (lane >> 3)][(lane & 7) * 8];  // waves 0,1 only

    // ---- prologue: stage tile 0 into buf 0 via regs ----
    {
        uint4 kreg = *(const uint4*)ksrc;
        *(uint4*)pKw = kreg;
        if (wave < 2) {
            uint4 vreg = *(const uint4*)vsrc;
            *(uint4*)pVw = vreg;
        }
    }
    __syncthreads();

    f32x4 acc0 = {0.f, 0.f, 0.f, 0.f}, acc1 = {0.f, 0.f, 0.f, 0.f};
    float m = -1e30f, l = 0.f;
    const f32x4 z = {0.f, 0.f, 0.f, 0.f};
    const int sw = lc & 7;
    const int vslot = ((lc & 1) << 2) + (g ^ ((lc >> 1) & 3));  // same for vlo/vhi

    // ---- hoisted per-lane LDS read base pointers (buf 0) ----
    const char* pKh = (const char*)&sK[0][lc][(g ^ sw) * 8];
    const char* pKl = (const char*)&sK[0][lc][((4 + g) ^ sw) * 8];
    const char* pV = (const char*)&sV[0][lc >> 1][vslot * 8];
    const char* kpre = ksrc + 4096;   // tile 1 source
    const char* vpre = vsrc + 2048;

    // one body per tile; PH = compile-time buffer index of the tile being computed.
    // Loads for tile t+1 issue FIRST (full tile of latency); ds_write lands after
    // compute, before the barrier.
#define GA_BODY(PH, DO_PRE)                                                       \
    do {                                                                          \
        uint4 kreg;                                                               \
        uint4 vreg;                                                               \
        if (DO_PRE) {                                                             \
            kreg = *(const uint4*)kpre;                                           \
            if (wave < 2) vreg = *(const uint4*)vpre;                             \
            kpre += 4096;                                                         \
            vpre += 2048;                                                         \
        }                                                                         \
        f32x4 d0, d1;                                                             \
        {                                                                         \
            s16x8 kh = *(const s16x8*)(pKh + (PH)*4096);                          \
            s16x8 kl = *(const s16x8*)(pKl + (PH)*4096);                          \
            f32x4 dd = __builtin_amdgcn_mfma_f32_16x16x32_bf16(kl, qh, z, 0, 0, 0); \
            dd = __builtin_amdgcn_mfma_f32_16x16x32_bf16(kh, ql, dd, 0, 0, 0);    \
            d0 = __builtin_amdgcn_mfma_f32_16x16x32_bf16(kh, qh, dd, 0, 0, 0);    \
        }                                                                         \
        {                                                                         \
            s16x8 kh = *(const s16x8*)(pKh + (PH)*4096 + 2048);                   \
            s16x8 kl = *(const s16x8*)(pKl + (PH)*4096 + 2048);                   \
            f32x4 dd = __builtin_amdgcn_mfma_f32_16x16x32_bf16(kl, qh, z, 0, 0, 0); \
            dd = __builtin_amdgcn_mfma_f32_16x16x32_bf16(kh, ql, dd, 0, 0, 0);    \
            d1 = __builtin_amdgcn_mfma_f32_16x16x32_bf16(kh, qh, dd, 0, 0, 0);    \
        }                                                                         \
        f32x4 kn20 = *(const f32x4*)(knt);                                        \
        f32x4 kn21 = *(const f32x4*)(knt + 16);                                   \
        knt += 32;                                                                \
        float sc[2][4];                                                           \
        {                                                                         \
            const f32x2 q2 = {qn2, qn2};                                          \
            f32x4 dm[2] = {d0, d1};                                               \
            f32x4 km[2] = {kn20, kn21};                                           \
            _Pragma("unroll") for (int st = 0; st < 2; st++) {                    \
                f32x2 kk0 = {km[st][0], km[st][1]}, kk1 = {km[st][2], km[st][3]}; \
                f32x2 dd0 = {dm[st][0], dm[st][1]}, dd1 = {dm[st][2], dm[st][3]}; \
                f32x2 e0 = dd0 - q2 * kk0;                                        \
                f32x2 e1 = dd1 - q2 * kk1;                                        \
                f32x2 t0 = dd0 * dd0 + e0;                                        \
                f32x2 t1 = dd1 * dd1 + e1;                                        \
                sc[st][0] = fminf(dm[st][0], t0[0]);                              \
                sc[st][1] = fminf(dm[st][1], t0[1]);                              \
                sc[st][2] = fminf(dm[st][2], t1[0]);                              \
                sc[st][3] = fminf(dm[st][3], t1[1]);                              \
            }                                                                     \
        }                                                                         \
        float tm = fmaxf(fmaxf(fmaxf(sc[0][0], sc[0][1]), fmaxf(sc[0][2], sc[0][3])), \
                         fmaxf(fmaxf(sc[1][0], sc[1][1]), fmaxf(sc[1][2], sc[1][3]))); \
        if (!__all(tm <= m + DEFER_THR)) {                                        \
            tm = fmaxf(tm, __shfl_xor(tm, 16));                                   \
            tm = fmaxf(tm, __shfl_xor(tm, 32));                                   \
            const float nm = fmaxf(m, tm);                                        \
            const float al = __builtin_amdgcn_exp2f((m - nm) * CSC);              \
            m = nm;                                                               \
            acc0 *= al;                                                           \
            acc1 *= al;                                                           \
            l *= al;                                                              \
        }                                                                         \
        const float negmC = -m * CSC;                                             \
        const f32x2 cscv = {CSC, CSC}, nmv = {negmC, negmC};                      \
        float p[2][4];                                                            \
        _Pragma("unroll") for (int st = 0; st < 2; st++) {                        \
            f32x2 s0 = {sc[st][0], sc[st][1]}, s1 = {sc[st][2], sc[st][3]};       \
            f32x2 e0 = s0 * cscv + nmv;                                           \
            f32x2 e1 = s1 * cscv + nmv;                                           \
            p[st][0] = __builtin_amdgcn_exp2f(e0[0]);                             \
            p[st][1] = __builtin_amdgcn_exp2f(e0[1]);                             \
            p[st][2] = __builtin_amdgcn_exp2f(e1[0]);                             \
            p[st][3] = __builtin_amdgcn_exp2f(e1[1]);                             \
        }                                                                         \
        l += ((p[0][0] + p[0][1]) + (p[0][2] + p[0][3])) +                        \
             ((p[1][0] + p[1][1]) + (p[1][2] + p[1][3]));                         \
        unsigned w00 = pk2(p[0][0], p[0][1]), w01 = pk2(p[0][2], p[0][3]);        \
        unsigned w10 = pk2(p[1][0], p[1][1]), w11 = pk2(p[1][2], p[1][3]);        \
        pl32(w00, w10);                                                           \
        pl32(w01, w11);                                                           \
        pl16(w00, w10);                                                           \
        pl16(w01, w11);                                                           \
        union { uint4 u; s16x8 v; } P;                                            \
        P.u = make_uint4(w00, w01, w10, w11);                                     \
        s16x8 vlo = *(const s16x8*)(pV + (PH)*2048);                              \
        s16x8 vhi = *(const s16x8*)(pV + (PH)*2048 + 1024);                       \
        acc0 = __builtin_amdgcn_mfma_f32_16x16x32_bf16(vlo, P.v, acc0, 0, 0, 0);  \
        acc1 = __builtin_amdgcn_mfma_f32_16x16x32_bf16(vhi, P.v, acc1, 0, 0, 0);  \
        if (DO_PRE) {                                                             \
            *(uint4*)((char*)pKw + ((PH) ^ 1) * 4096) = kreg;                     \
            if (wave < 2) *(uint4*)((char*)pVw + ((PH) ^ 1) * 2048) = vreg;       \
        }                                                                         \
        __syncthreads();                                                          \
    } while (0)

#pragma unroll 1
    for (int t2 = 0; t2 < NT / 2; ++t2) {
        GA_BODY(0, 1);                  // tile 2*t2   (buf0); stage 2*t2+1 -> buf1
        GA_BODY(1, (t2 < NT / 2 - 1));  // tile 2*t2+1 (buf1); stage 2*t2+2 -> buf0
    }
#undef GA_BODY

    // ---- cross-g row-sum, write fp32 partials ----
    l += __shfl_xor(l, 16);
    l += __shfl_xor(l, 32);
    float* pa = pacc + (((size_t)bh * STRIPS + strip) * NL + (qw + lc)) * 32;
    *(f32x4*)(pa + 4 * g) = acc0;
    *(f32x4*)(pa + 16 + 4 * g) = acc1;
    if (g == 0) {
        *(float2*)(pml + (((size_t)bh * STRIPS + strip) * NL + (qw + lc)) * 2) =
            make_float2(m, l);
    }
}

// ==== combine kernel (4 strips) ====
__global__ __launch_bounds__(256) void ga_combine(const float* __restrict__ pacc,
                                                  const float* __restrict__ pml,
                                                  float* __restrict__ O) {
    const int tid = blockIdx.x * 256 + threadIdx.x;
    const int dq = tid & 7, q = (tid >> 3) & 2047, bh = tid >> 14;
    const int b = bh >> 3, h = bh & 7;
    float m[4], l[4];
#pragma unroll
    for (int s = 0; s < 4; s++) {
        float2 t = *(const float2*)(pml + (((size_t)bh * STRIPS + s) * NL + q) * 2);
        m[s] = t.x;
        l[s] = t.y;
    }
    float mf = fmaxf(fmaxf(m[0], m[1]), fmaxf(m[2], m[3]));
    float w[4], L = 0.f;
#pragma unroll
    for (int s = 0; s < 4; s++) {
        w[s] = __builtin_amdgcn_exp2f((m[s] - mf) * CSC);
        L = fmaf(l[s], w[s], L);
    }
    const float inv = 1.f / L;
    float4 o = make_float4(0.f, 0.f, 0.f, 0.f);
#pragma unroll
    for (int s = 0; s < 4; s++) {
        const float* pa = pacc + (((size_t)bh * STRIPS + s) * NL + q) * 32 + dq * 4;
        float4 a = *(const float4*)pa;
        o.x = fmaf(a.x, w[s], o.x);
        o.y = fmaf(a.y, w[s], o.y);
        o.z = fmaf(a.z, w[s], o.z);
        o.w = fmaf(a.w, w[s], o.w);
    }
    o.x *= inv; o.y *= inv; o.z *= inv; o.w *= inv;
    *(float4*)(O + (((size_t)(b * NL + q)) * NH + h) * 32 + dq * 4) = o;
}

// ==== fallback: round-4 kernel (validated), used only if ws too small ====
__global__ __launch_bounds__(512, 4) void ga_fallback(
    const float* __restrict__ Q, const float* __restrict__ K,
    const float* __restrict__ V, float* __restrict__ O) {
    __shared__ union {
        struct {
            u16 Kh[2][64][32];
            u16 Kl[2][64][32];
            u16 Vt[2][32][64];
            float kn2[2][64];
        } s;
        struct { float acc[8][32][17]; float m[8][16]; float l[8][16]; } c;
    } u;
    __shared__ u16 sP[8][16][64];

    const int T = threadIdx.x;
    const int lane = T & 63, wave = T >> 6;
    const int g = lane >> 4, lc = lane & 15, g8 = g * 8;
    const int half = wave >> 2;
    const int qt = blockIdx.x & 31;
    const int bh = blockIdx.x >> 5;
    const int b = bh >> 3, h = bh & 7;
    const int qw = qt * 64 + (wave & 3) * 16;

    const float* qrow = Q + ((size_t)((b * NL + qw + lc) * NH + h)) * 32 + g8;
    float4 qa = *(const float4*)qrow, qb = *(const float4*)(qrow + 4);
    float q8[8] = {qa.x, qa.y, qa.z, qa.w, qb.x, qb.y, qb.z, qb.w};
    union { unsigned u4[4]; s16x8 v; } qh_, ql_;
    float qn2 = 0.f;
#pragma unroll
    for (int i = 0; i < 4; i++) {
        float x0 = q8[2 * i], x1 = q8[2 * i + 1];
        qn2 = fmaf(x0, x0, qn2);
        qn2 = fmaf(x1, x1, qn2);
        unsigned h01 = pk2(x0, x1);
        qh_.u4[i] = h01;
        float h0 = __uint_as_float(h01 << 16);
        float h1 = __uint_as_float(h01 & 0xffff0000u);
        ql_.u4[i] = pk2(x0 - h0, x1 - h1);
    }
    const s16x8 qh = qh_.v, ql = ql_.v;
    qn2 += __shfl_xor(qn2, 16);
    qn2 += __shfl_xor(qn2, 32);

    const int Tl = T & 255;
    const int sk = Tl >> 2, kc = Tl & 3;
    const int dv = Tl & 31, vc = Tl >> 5;
    const float* kbase = K + ((size_t)(b * NS * NH) + h) * 32;
    const float* vbase = V + ((size_t)(b * NS * NH) + h) * 32;
    const int kphys = (kc ^ swzK(sk)) * 8;
    const int vphys = (vc ^ swzV(dv)) * 8;

    int s0 = half * 1024;
    float4 ka = *(const float4*)(kbase + (size_t)(s0 + sk) * 256 + kc * 8);
    float4 kb = *(const float4*)(kbase + (size_t)(s0 + sk) * 256 + kc * 8 + 4);
    float vr[8];
#pragma unroll
    for (int i = 0; i < 8; i++) vr[i] = vbase[(size_t)(s0 + 8 * vc + i) * 256 + dv];

    f32x4 acc0 = {0.f, 0.f, 0.f, 0.f}, acc1 = {0.f, 0.f, 0.f, 0.f};
    float m = -INFINITY, l = 0.f;

    for (int t = 0; t < 16; ++t) {
        {
            float kx[8] = {ka.x, ka.y, ka.z, ka.w, kb.x, kb.y, kb.z, kb.w};
            unsigned hh[4], ll[4];
            float kn2p = 0.f;
#pragma unroll
            for (int i = 0; i < 4; i++) {
                float x0 = kx[2 * i], x1 = kx[2 * i + 1];
                kn2p = fmaf(x0, x0, kn2p);
                kn2p = fmaf(x1, x1, kn2p);
                unsigned h01 = pk2(x0, x1);
                hh[i] = h01;
                float h0 = __uint_as_float(h01 << 16);
                float h1 = __uint_as_float(h01 & 0xffff0000u);
                ll[i] = pk2(x0 - h0, x1 - h1);
            }
            *(uint4*)&u.s.Kh[half][sk][kphys] = make_uint4(hh[0], hh[1], hh[2], hh[3]);
            *(uint4*)&u.s.Kl[half][sk][kphys] = make_uint4(ll[0], ll[1], ll[2], ll[3]);
            kn2p = dpp_add<0xB1>(kn2p);
            kn2p = dpp_add<0x4E>(kn2p);
            if (kc == 0) u.s.kn2[half][sk] = kn2p;
            *(uint4*)&u.s.Vt[half][dv][vphys] =
                make_uint4(pk2(vr[0], vr[1]), pk2(vr[2], vr[3]),
                           pk2(vr[4], vr[5]), pk2(vr[6], vr[7]));
        }
        const int tn = (t + 1 < 16) ? t + 1 : t;
        const int sn = half * 1024 + tn * 64;
        ka = *(const float4*)(kbase + (size_t)(sn + sk) * 256 + kc * 8);
        kb = *(const float4*)(kbase + (size_t)(sn + sk) * 256 + kc * 8 + 4);
#pragma unroll
        for (int i = 0; i < 8; i++) vr[i] = vbase[(size_t)(sn + 8 * vc + i) * 256 + dv];

        __syncthreads();

        f32x4 d[4], kn2v[4];
        const f32x4 z = {0.f, 0.f, 0.f, 0.f};
        const int skr = swzK(lc);
#pragma unroll
        for (int st = 0; st < 4; st++) {
            kn2v[st] = *(f32x4*)&u.s.kn2[half][16 * st + 4 * g];
            s16x8 kh = *(s16x8*)&u.s.Kh[half][16 * st + lc][(g ^ skr) * 8];
            s16x8 kl = *(s16x8*)&u.s.Kl[half][16 * st + lc][(g ^ skr) * 8];
            f32x4 dd = __builtin_amdgcn_mfma_f32_16x16x32_bf16(kl, qh, z, 0, 0, 0);
            dd = __builtin_amdgcn_mfma_f32_16x16x32_bf16(kh, ql, dd, 0, 0, 0);
            dd = __builtin_amdgcn_mfma_f32_16x16x32_bf16(kh, qh, dd, 0, 0, 0);
            d[st] = dd;
        }

        float sc[4][4];
#pragma unroll
        for (int st = 0; st < 4; st++)
#pragma unroll
            for (int r = 0; r < 4; r++) {
                float dd = d[st][r];
                float w = fmaxf(fmaf(-dd, dd, qn2 * kn2v[st][r]), 0.f);
                sc[st][r] = (dd - w) * CSC;
            }

        float x0 = fmaxf(fmaxf(sc[0][0], sc[0][1]), fmaxf(sc[0][2], sc[0][3]));
        float x1 = fmaxf(fmaxf(sc[1][0], sc[1][1]), fmaxf(sc[1][2], sc[1][3]));
        float x2 = fmaxf(fmaxf(sc[2][0], sc[2][1]), fmaxf(sc[2][2], sc[2][3]));
        float x3 = fmaxf(fmaxf(sc[3][0], sc[3][1]), fmaxf(sc[3][2], sc[3][3]));
        float tm = fmaxf(fmaxf(x0, x1), fmaxf(x2, x3));
        tm = fmaxf(tm, __shfl_xor(tm, 16));
        tm = fmaxf(tm, __shfl_xor(tm, 32));
        const float nm = fmaxf(m, tm);
        const float al = __builtin_amdgcn_exp2f(m - nm);
        m = nm;
        float p[4][4], ls = 0.f;
#pragma unroll
        for (int st = 0; st < 4; st++)
#pragma unroll
            for (int r = 0; r < 4; r++) {
                p[st][r] = __builtin_amdgcn_exp2f(sc[st][r] - nm);
                ls += p[st][r];
            }
        l = fmaf(l, al, ls);
        acc0 *= al;
        acc1 *= al;

#pragma unroll
        for (int st = 0; st < 4; st++) {
            const int off = ((2 * st + (g >> 1)) ^ (lc & 7)) * 8 + (g & 1) * 4;
            *(uint2*)&sP[wave][lc][off] =
                make_uint2(pk2(p[st][0], p[st][1]), pk2(p[st][2], p[st][3]));
        }
        __builtin_amdgcn_s_waitcnt(0xC07F);

        const int svl = swzV(lc), svh = swzV(lc + 16), spl = lc & 7;
        s16x8 va00 = *(s16x8*)&u.s.Vt[half][lc][(g ^ svl) * 8];
        s16x8 va01 = *(s16x8*)&u.s.Vt[half][lc][((4 + g) ^ svl) * 8];
        s16x8 va10 = *(s16x8*)&u.s.Vt[half][lc + 16][(g ^ svh) * 8];
        s16x8 va11 = *(s16x8*)&u.s.Vt[half][lc + 16][((4 + g) ^ svh) * 8];
        s16x8 pb0 = *(s16x8*)&sP[wave][lc][(g ^ spl) * 8];
        s16x8 pb1 = *(s16x8*)&sP[wave][lc][((4 + g) ^ spl) * 8];
        acc0 = __builtin_amdgcn_mfma_f32_16x16x32_bf16(va00, pb0, acc0, 0, 0, 0);
        acc0 = __builtin_amdgcn_mfma_f32_16x16x32_bf16(va01, pb1, acc0, 0, 0, 0);
        acc1 = __builtin_amdgcn_mfma_f32_16x16x32_bf16(va10, pb0, acc1, 0, 0, 0);
        acc1 = __builtin_amdgcn_mfma_f32_16x16x32_bf16(va11, pb1, acc1, 0, 0, 0);

        __syncthreads();
    }

    l += __shfl_xor(l, 16);
    l += __shfl_xor(l, 32);
#pragma unroll
    for (int r = 0; r < 4; r++) {
        u.c.acc[wave][4 * g + r][lc] = acc0[r];
        u.c.acc[wave][16 + 4 * g + r][lc] = acc1[r];
    }
    if (lane < 16) {
        u.c.m[wave][lc] = m;
        u.c.l[wave][lc] = l;
    }
    __syncthreads();

    const int q = T >> 3, dq = (T & 7) * 4, qr = q & 15;
    const int w0 = q >> 4, w1 = w0 + 4;
    float m0 = u.c.m[w0][qr], m1 = u.c.m[w1][qr];
    float l0 = u.c.l[w0][qr], l1 = u.c.l[w1][qr];
    float mf = fmaxf(m0, m1);
    float e0 = __builtin_amdgcn_exp2f(m0 - mf);
    float e1 = __builtin_amdgcn_exp2f(m1 - mf);
    float inv = 1.f / fmaf(l1, e1, l0 * e0);
    e0 *= inv;
    e1 *= inv;
    float4 o;
    o.x = u.c.acc[w0][dq + 0][qr] * e0 + u.c.acc[w1][dq + 0][qr] * e1;
    o.y = u.c.acc[w0][dq + 1][qr] * e0 + u.c.acc[w1][dq + 1][qr] * e1;
    o.z = u.c.acc[w0][dq + 2][qr] * e0 + u.c.acc[w1][dq + 2][qr] * e1;
    o.w = u.c.acc[w0][dq + 3][qr] * e0 + u.c.acc[w1][dq + 3][qr] * e1;
    *(float4*)(O + ((size_t)((b * NL + qt * 64 + q) * NH + h)) * 32 + dq) = o;
}

extern "C" void kernel_launch(void* const* d_in, const int* in_sizes, int n_in,
                              void* d_out, int out_size, void* d_ws, size_t ws_size,
                              hipStream_t stream) {
    const float* Q = (const float*)d_in[0];
    const float* K = (const float*)d_in[1];
    const float* V = (const float*)d_in[2];
    float* O = (float*)d_out;

    if (ws_size >= (size_t)WS_NEED) {
        float* kn2w = (float*)((char*)d_ws + WS_KN2_OFF);
        u16* khkl = (u16*)((char*)d_ws + WS_KHKL_OFF);
        u16* vtw = (u16*)((char*)d_ws + WS_VT_OFF);
        float* pacc = (float*)((char*)d_ws + WS_PACC_OFF);
        float* pml = (float*)((char*)d_ws + WS_PML_OFF);
        ga_pre<<<NBH * 32, 256, 0, stream>>>(K, V, kn2w, khkl, vtw);
        // grid = 32 qt-blocks x 64 (bh,strip) groups = 2048 (matches qt=blk>>6)
        ga_lean<<<NBH * 32 * STRIPS, 256, 0, stream>>>(Q, kn2w, khkl, vtw, pacc, pml);
        ga_combine<<<(NBH * NL * 8) / 256, 256, 0, stream>>>(pacc, pml, O);
    } else {
        ga_fallback<<<NBH * 32, 512, 0, stream>>>(Q, K, V, O);
    }
}

// Round 13
// 103.369 us; speedup vs baseline: 1.0604x; 1.0604x over previous
//
#include <hip/hip_runtime.h>
#include <hip/hip_bf16.h>
#include <math.h>

// GeomAttention: B=2, L=S=2048, H=8, E=D=32, fp32 in/out.
// scores = (0.5*dot - 0.5*relu(qn2*kn2 - dot^2))/sqrt(E); softmax over S; out = attn@V.
// FINAL (revert to R11 best = 105.4us total, main 45.3us): R12's reg-staging
// test regressed (48.7us) and exonerated global_load_lds — the last suspect.
// Falsification matrix complete: barriers (R5), LDS conflicts (0), LDS BW (R4),
// occupancy (R10: 49%), VALU overhead (R11), reg pipelining (R2/R7), DMA (R12)
// — all nulled. Main kernel pinned at 45.2+-0.2us across 7 structures with all
// pipes <50%; total = fill(47, harness-fixed) + pre(8) + main(45) + combine(6.5).
// This source == R11: 16q/wave, 32-key tiles, launch_bounds(256,8), grid 2048,
// LDS 12.25KB, conflict-free layouts (128B rows, <=8 lanes/slot), DMA staging,
// hoisted LDS base pointers + manual 2x unroll, permlane P^T, defer-max.

#define NB 2
#define NL 2048
#define NS 2048
#define NH 8
#define NBH 16
#define STRIPS 4
#define NT 16                 // 32-key tiles per 512-key strip
#define CSC 0.12751742f       // 0.5 / sqrt(32) * log2(e)
#define DEFER_THR 24.0f       // p <= 2^(24*CSC) ~= 8.4, safe in bf16

#define WS_KN2_OFF 0u
#define WS_KHKL_OFF 131072u                          // 16*2048 f32
#define WS_VT_OFF (131072u + 4194304u)               // + 16*2048*128B (K hi/lo image)
#define WS_PACC_OFF (131072u + 4194304u + 2097152u)  // + 16*64*2048B (V^T tile-major image)
#define WS_PML_OFF (WS_PACC_OFF + 16777216u)         // + 16*4*2048*32 f32
#define WS_NEED (WS_PML_OFF + 1048576u)              // + 16*4*2048*2 f32 = 24,248,320 B

typedef float f32x4 __attribute__((ext_vector_type(4)));
typedef float f32x2 __attribute__((ext_vector_type(2)));
typedef short s16x8 __attribute__((ext_vector_type(8)));
typedef unsigned short u16;

__device__ inline unsigned pk2(float a, float b) {  // bf16(a)|bf16(b)<<16, RNE
    __hip_bfloat162 t = __float22bfloat162_rn(make_float2(a, b));
    union { __hip_bfloat162 h; unsigned u; } cv;
    cv.h = t;
    return cv.u;
}
template <int CTRL>
__device__ inline float dpp_add(float x) {
    return x + __int_as_float(__builtin_amdgcn_mov_dpp(__float_as_int(x), CTRL, 0xF, 0xF, false));
}
// async global->LDS DMA, 16 B/lane; LDS dest = uniform base + lane*16 [m97/m104]
__device__ inline void dma16(const void* gp, void* lp) {
    __builtin_amdgcn_global_load_lds(
        (__attribute__((address_space(1))) void*)(void*)gp,
        (__attribute__((address_space(3))) void*)lp, 16, 0, 0);
}
// gfx950 cross-lane row swaps (both operands read-write)
__device__ inline void pl32(unsigned& a, unsigned& b) {
    asm("v_permlane32_swap_b32 %0, %1" : "+v"(a), "+v"(b));
}
__device__ inline void pl16(unsigned& a, unsigned& b) {
    asm("v_permlane16_swap_b32 %0, %1" : "+v"(a), "+v"(b));
}
// fallback-kernel swizzles
__device__ inline int swzK(int row) { return (row ^ (row >> 2)) & 3; }
__device__ inline int swzV(int row) { return (row + (row >> 3)) & 7; }

// ==== pre-kernel ====
// K image: [bh][key][8 chunks x 16B], phys = logical ^ (key&7); 0-3 hi, 4-7 lo.
// V image: tile-major [bh][tile(32k)][16 rows x 128B]; row r holds d={2r,2r+1},
//          slot = (d&1)*4 + (c2 ^ (r&3)), c2 = 8-key chunk within tile. kn2 fp32.
__global__ __launch_bounds__(256) void ga_pre(const float* __restrict__ K,
                                              const float* __restrict__ V,
                                              float* __restrict__ kn2w,
                                              u16* __restrict__ khkl,
                                              u16* __restrict__ vtw) {
    __shared__ float Vf[64][36];
    const int T = threadIdx.x;
    const int bh = blockIdx.x >> 5, stile = blockIdx.x & 31;
    const int b = bh >> 3, h = bh & 7;
    const int s0 = stile * 64;
    const int sk = T >> 2, kc = T & 3;

    const float* kp = K + ((size_t)((b * NS + s0 + sk) * NH + h)) * 32 + kc * 8;
    float4 f0 = *(const float4*)kp, f1 = *(const float4*)(kp + 4);
    float kx[8] = {f0.x, f0.y, f0.z, f0.w, f1.x, f1.y, f1.z, f1.w};
    unsigned hh[4], ll[4];
    float kn2p = 0.f;
#pragma unroll
    for (int i = 0; i < 4; i++) {
        float x0 = kx[2 * i], x1 = kx[2 * i + 1];
        kn2p = fmaf(x0, x0, kn2p);
        kn2p = fmaf(x1, x1, kn2p);
        unsigned h01 = pk2(x0, x1);
        hh[i] = h01;
        float h0 = __uint_as_float(h01 << 16);
        float h1 = __uint_as_float(h01 & 0xffff0000u);
        ll[i] = pk2(x0 - h0, x1 - h1);
    }
    u16* kd = khkl + ((size_t)(bh * NS + s0 + sk)) * 64;
    const int swk = sk & 7;
    *(uint4*)(kd + ((kc ^ swk) * 8)) = make_uint4(hh[0], hh[1], hh[2], hh[3]);
    *(uint4*)(kd + (((4 + kc) ^ swk) * 8)) = make_uint4(ll[0], ll[1], ll[2], ll[3]);
    kn2p = dpp_add<0xB1>(kn2p);
    kn2p = dpp_add<0x4E>(kn2p);
    if (kc == 0) kn2w[bh * NS + s0 + sk] = kn2p;

    const float* vp = V + ((size_t)((b * NS + s0 + sk) * NH + h)) * 32 + kc * 8;
    float4 g0 = *(const float4*)vp, g1 = *(const float4*)(vp + 4);
    // chunk swizzle keyed on (row>>3)&3 so the column-wise read below is <=2-way banked
    const int chv = kc ^ ((sk >> 3) & 3);
    *(float4*)&Vf[sk][chv * 8] = g0;
    *(float4*)&Vf[sk][chv * 8 + 4] = g1;
    __syncthreads();
    const int dr = T >> 3, c = T & 7;  // dr = d-row 0..31, c = 8-key chunk in 64-key stile
    float vv[8];
#pragma unroll
    for (int i = 0; i < 8; i++)
        vv[i] = Vf[c * 8 + i][(((dr >> 3) ^ (c & 3)) << 3) + (dr & 7)];
    // tile-major store: tile tt, row r = dr>>1, slot = (dr&1)*4 + ((c&3) ^ (r&3))
    const int tt = (s0 >> 5) + (c >> 2);
    const int r = dr >> 1;
    const int slot = ((dr & 1) << 2) + ((c & 3) ^ (r & 3));
    *(uint4*)(vtw + (size_t)bh * 65536 + tt * 1024 + r * 64 + slot * 8) =
        make_uint4(pk2(vv[0], vv[1]), pk2(vv[2], vv[3]), pk2(vv[4], vv[5]), pk2(vv[6], vv[7]));
}

// ==== main kernel: lean, VGPR<=64, 8 blocks/CU, unrolled x2, hoisted addrs ====
__global__ __launch_bounds__(256, 8) void ga_lean(
    const float* __restrict__ Q, const float* __restrict__ kn2w,
    const u16* __restrict__ khkl, const u16* __restrict__ vtw,
    float* __restrict__ pacc, float* __restrict__ pml) {
    __shared__ u16 sK[2][32][64];  // [buf][key][8 phys chunks x 8 u16]  8 KB
    __shared__ u16 sV[2][16][64];  // [buf][row=d>>1][8 slots x 8 u16]   4 KB

    const int T = threadIdx.x;
    const int lane = T & 63, wave = T >> 6;
    const int g = lane >> 4, lc = lane & 15, g8 = g * 8;
    // XCD grouping: same (bh,strip) group's 32 qt-blocks are 64 apart -> same XCD.
    const int blk = blockIdx.x;
    const int qt = blk >> 6, grp = blk & 63;  // grid 2048: qt 0..31
    const int bh = grp >> 2, strip = grp & 3;
    const int b = bh >> 3, h = bh & 7;
    const int qw = qt * 64 + wave * 16;
    const int kb0 = strip * 512;

    // ---- Q fragment (hi/lo bf16) + exact qn2 ----
    const float* qrow = Q + ((size_t)((b * NL + qw + lc) * NH + h)) * 32 + g8;
    float4 qa = *(const float4*)qrow, qb = *(const float4*)(qrow + 4);
    float q8[8] = {qa.x, qa.y, qa.z, qa.w, qb.x, qb.y, qb.z, qb.w};
    union { unsigned u4[4]; s16x8 v; } qh_, ql_;
    float qn2 = 0.f;
#pragma unroll
    for (int i = 0; i < 4; i++) {
        float x0 = q8[2 * i], x1 = q8[2 * i + 1];
        qn2 = fmaf(x0, x0, qn2);
        qn2 = fmaf(x1, x1, qn2);
        unsigned h01 = pk2(x0, x1);
        qh_.u4[i] = h01;
        float h0 = __uint_as_float(h01 << 16);
        float h1 = __uint_as_float(h01 & 0xffff0000u);
        ql_.u4[i] = pk2(x0 - h0, x1 - h1);
    }
    const s16x8 qh = qh_.v, ql = ql_.v;
    qn2 += __shfl_xor(qn2, 16);
    qn2 += __shfl_xor(qn2, 32);

    // ---- DMA sources (contiguous 1KB per dma; advanced by += constants) ----
    const char* ksrc = (const char*)khkl + ((size_t)(bh * NS + kb0 + 8 * wave)) * 128 + lane * 16;
    const char* vsrc = (const char*)vtw + ((size_t)bh * 65536 + (kb0 >> 5) * 1024) * 2 +
                       wave * 1024 + lane * 16;
    const float* knt = kn2w + (size_t)bh * NS + kb0 + 4 * g;

    // ---- prologue: stage tile 0 into buf 0 ----
    dma16(ksrc, &sK[0][8 * wave][0]);
    if (wave < 2) dma16(vsrc, &sV[0][8 * wave][0]);
    __syncthreads();  // drains vmcnt -> tile 0 in LDS

    f32x4 acc0 = {0.f, 0.f, 0.f, 0.f}, acc1 = {0.f, 0.f, 0.f, 0.f};
    float m = -1e30f, l = 0.f;
    const f32x4 z = {0.f, 0.f, 0.f, 0.f};
    const int sw = lc & 7;
    const int vslot = ((lc & 1) << 2) + (g ^ ((lc >> 1) & 3));  // same for vlo/vhi

    // ---- hoisted per-lane LDS base pointers (buf 0); buf1/subtile via const offs ----
    // sK row stride 128B, buf stride 4096B; (4+g)^sw == (g^sw)^4 -> separate base.
    const char* pKh = (const char*)&sK[0][lc][(g ^ sw) * 8];
    const char* pKl = (const char*)&sK[0][lc][((4 + g) ^ sw) * 8];
    const char* pV = (const char*)&sV[0][lc >> 1][vslot * 8];
    const char* kpre = ksrc + 4096;   // tile 1 source
    const char* vpre = vsrc + 2048;

    // one body per tile; PH = compile-time buffer index of the tile being computed
#define GA_BODY(PH, DO_PRE)                                                       \
    do {                                                                          \
        if (DO_PRE) {                                                             \
            dma16(kpre, &sK[PH ^ 1][8 * wave][0]);                                \
            if (wave < 2) dma16(vpre, &sV[PH ^ 1][8 * wave][0]);                  \
            kpre += 4096;                                                         \
            vpre += 2048;                                                         \
        }                                                                         \
        f32x4 d0, d1;                                                             \
        {                                                                         \
            s16x8 kh = *(const s16x8*)(pKh + (PH)*4096);                          \
            s16x8 kl = *(const s16x8*)(pKl + (PH)*4096);                          \
            f32x4 dd = __builtin_amdgcn_mfma_f32_16x16x32_bf16(kl, qh, z, 0, 0, 0); \
            dd = __builtin_amdgcn_mfma_f32_16x16x32_bf16(kh, ql, dd, 0, 0, 0);    \
            d0 = __builtin_amdgcn_mfma_f32_16x16x32_bf16(kh, qh, dd, 0, 0, 0);    \
        }                                                                         \
        {                                                                         \
            s16x8 kh = *(const s16x8*)(pKh + (PH)*4096 + 2048);                   \
            s16x8 kl = *(const s16x8*)(pKl + (PH)*4096 + 2048);                   \
            f32x4 dd = __builtin_amdgcn_mfma_f32_16x16x32_bf16(kl, qh, z, 0, 0, 0); \
            dd = __builtin_amdgcn_mfma_f32_16x16x32_bf16(kh, ql, dd, 0, 0, 0);    \
            d1 = __builtin_amdgcn_mfma_f32_16x16x32_bf16(kh, qh, dd, 0, 0, 0);    \
        }                                                                         \
        f32x4 kn20 = *(const f32x4*)(knt);                                        \
        f32x4 kn21 = *(const f32x4*)(knt + 16);                                   \
        knt += 32;                                                                \
        float sc[2][4];                                                           \
        {                                                                         \
            const f32x2 q2 = {qn2, qn2};                                          \
            f32x4 dm[2] = {d0, d1};                                               \
            f32x4 km[2] = {kn20, kn21};                                           \
            _Pragma("unroll") for (int st = 0; st < 2; st++) {                    \
                f32x2 kk0 = {km[st][0], km[st][1]}, kk1 = {km[st][2], km[st][3]}; \
                f32x2 dd0 = {dm[st][0], dm[st][1]}, dd1 = {dm[st][2], dm[st][3]}; \
                f32x2 e0 = dd0 - q2 * kk0;                                        \
                f32x2 e1 = dd1 - q2 * kk1;                                        \
                f32x2 t0 = dd0 * dd0 + e0;                                        \
                f32x2 t1 = dd1 * dd1 + e1;                                        \
                sc[st][0] = fminf(dm[st][0], t0[0]);                              \
                sc[st][1] = fminf(dm[st][1], t0[1]);                              \
                sc[st][2] = fminf(dm[st][2], t1[0]);                              \
                sc[st][3] = fminf(dm[st][3], t1[1]);                              \
            }                                                                     \
        }                                                                         \
        float tm = fmaxf(fmaxf(fmaxf(sc[0][0], sc[0][1]), fmaxf(sc[0][2], sc[0][3])), \
                         fmaxf(fmaxf(sc[1][0], sc[1][1]), fmaxf(sc[1][2], sc[1][3]))); \
        if (!__all(tm <= m + DEFER_THR)) {                                        \
            tm = fmaxf(tm, __shfl_xor(tm, 16));                                   \
            tm = fmaxf(tm, __shfl_xor(tm, 32));                                   \
            const float nm = fmaxf(m, tm);                                        \
            const float al = __builtin_amdgcn_exp2f((m - nm) * CSC);              \
            m = nm;                                                               \
            acc0 *= al;                                                           \
            acc1 *= al;                                                           \
            l *= al;                                                              \
        }                                                                         \
        const float negmC = -m * CSC;                                             \
        const f32x2 cscv = {CSC, CSC}, nmv = {negmC, negmC};                      \
        float p[2][4];                                                            \
        _Pragma("unroll") for (int st = 0; st < 2; st++) {                        \
            f32x2 s0 = {sc[st][0], sc[st][1]}, s1 = {sc[st][2], sc[st][3]};       \
            f32x2 e0 = s0 * cscv + nmv;                                           \
            f32x2 e1 = s1 * cscv + nmv;                                           \
            p[st][0] = __builtin_amdgcn_exp2f(e0[0]);                             \
            p[st][1] = __builtin_amdgcn_exp2f(e0[1]);                             \
            p[st][2] = __builtin_amdgcn_exp2f(e1[0]);                             \
            p[st][3] = __builtin_amdgcn_exp2f(e1[1]);                             \
        }                                                                         \
        l += ((p[0][0] + p[0][1]) + (p[0][2] + p[0][3])) +                        \
             ((p[1][0] + p[1][1]) + (p[1][2] + p[1][3]));                         \
        unsigned w00 = pk2(p[0][0], p[0][1]), w01 = pk2(p[0][2], p[0][3]);        \
        unsigned w10 = pk2(p[1][0], p[1][1]), w11 = pk2(p[1][2], p[1][3]);        \
        pl32(w00, w10);                                                           \
        pl32(w01, w11);                                                           \
        pl16(w00, w10);                                                           \
        pl16(w01, w11);                                                           \
        union { uint4 u; s16x8 v; } P;                                            \
        P.u = make_uint4(w00, w01, w10, w11);                                     \
        s16x8 vlo = *(const s16x8*)(pV + (PH)*2048);                              \
        s16x8 vhi = *(const s16x8*)(pV + (PH)*2048 + 1024);                       \
        acc0 = __builtin_amdgcn_mfma_f32_16x16x32_bf16(vlo, P.v, acc0, 0, 0, 0);  \
        acc1 = __builtin_amdgcn_mfma_f32_16x16x32_bf16(vhi, P.v, acc1, 0, 0, 0);  \
        __syncthreads();                                                          \
    } while (0)

#pragma unroll 1
    for (int t2 = 0; t2 < NT / 2; ++t2) {
        GA_BODY(0, 1);            // tile 2*t2   (buf0); prefetch 2*t2+1 (always valid)
        GA_BODY(1, (t2 < NT / 2 - 1));  // tile 2*t2+1 (buf1); prefetch 2*t2+2
    }
#undef GA_BODY

    // ---- cross-g row-sum, write fp32 partials ----
    l += __shfl_xor(l, 16);
    l += __shfl_xor(l, 32);
    float* pa = pacc + (((size_t)bh * STRIPS + strip) * NL + (qw + lc)) * 32;
    *(f32x4*)(pa + 4 * g) = acc0;
    *(f32x4*)(pa + 16 + 4 * g) = acc1;
    if (g == 0) {
        *(float2*)(pml + (((size_t)bh * STRIPS + strip) * NL + (qw + lc)) * 2) =
            make_float2(m, l);
    }
}

// ==== combine kernel (4 strips) ====
__global__ __launch_bounds__(256) void ga_combine(const float* __restrict__ pacc,
                                                  const float* __restrict__ pml,
                                                  float* __restrict__ O) {
    const int tid = blockIdx.x * 256 + threadIdx.x;
    const int dq = tid & 7, q = (tid >> 3) & 2047, bh = tid >> 14;
    const int b = bh >> 3, h = bh & 7;
    float m[4], l[4];
#pragma unroll
    for (int s = 0; s < 4; s++) {
        float2 t = *(const float2*)(pml + (((size_t)bh * STRIPS + s) * NL + q) * 2);
        m[s] = t.x;
        l[s] = t.y;
    }
    float mf = fmaxf(fmaxf(m[0], m[1]), fmaxf(m[2], m[3]));
    float w[4], L = 0.f;
#pragma unroll
    for (int s = 0; s < 4; s++) {
        w[s] = __builtin_amdgcn_exp2f((m[s] - mf) * CSC);
        L = fmaf(l[s], w[s], L);
    }
    const float inv = 1.f / L;
    float4 o = make_float4(0.f, 0.f, 0.f, 0.f);
#pragma unroll
    for (int s = 0; s < 4; s++) {
        const float* pa = pacc + (((size_t)bh * STRIPS + s) * NL + q) * 32 + dq * 4;
        float4 a = *(const float4*)pa;
        o.x = fmaf(a.x, w[s], o.x);
        o.y = fmaf(a.y, w[s], o.y);
        o.z = fmaf(a.z, w[s], o.z);
        o.w = fmaf(a.w, w[s], o.w);
    }
    o.x *= inv; o.y *= inv; o.z *= inv; o.w *= inv;
    *(float4*)(O + (((size_t)(b * NL + q)) * NH + h) * 32 + dq * 4) = o;
}

// ==== fallback: round-4 kernel (validated), used only if ws too small ====
__global__ __launch_bounds__(512, 4) void ga_fallback(
    const float* __restrict__ Q, const float* __restrict__ K,
    const float* __restrict__ V, float* __restrict__ O) {
    __shared__ union {
        struct {
            u16 Kh[2][64][32];
            u16 Kl[2][64][32];
            u16 Vt[2][32][64];
            float kn2[2][64];
        } s;
        struct { float acc[8][32][17]; float m[8][16]; float l[8][16]; } c;
    } u;
    __shared__ u16 sP[8][16][64];

    const int T = threadIdx.x;
    const int lane = T & 63, wave = T >> 6;
    const int g = lane >> 4, lc = lane & 15, g8 = g * 8;
    const int half = wave >> 2;
    const int qt = blockIdx.x & 31;
    const int bh = blockIdx.x >> 5;
    const int b = bh >> 3, h = bh & 7;
    const int qw = qt * 64 + (wave & 3) * 16;

    const float* qrow = Q + ((size_t)((b * NL + qw + lc) * NH + h)) * 32 + g8;
    float4 qa = *(const float4*)qrow, qb = *(const float4*)(qrow + 4);
    float q8[8] = {qa.x, qa.y, qa.z, qa.w, qb.x, qb.y, qb.z, qb.w};
    union { unsigned u4[4]; s16x8 v; } qh_, ql_;
    float qn2 = 0.f;
#pragma unroll
    for (int i = 0; i < 4; i++) {
        float x0 = q8[2 * i], x1 = q8[2 * i + 1];
        qn2 = fmaf(x0, x0, qn2);
        qn2 = fmaf(x1, x1, qn2);
        unsigned h01 = pk2(x0, x1);
        qh_.u4[i] = h01;
        float h0 = __uint_as_float(h01 << 16);
        float h1 = __uint_as_float(h01 & 0xffff0000u);
        ql_.u4[i] = pk2(x0 - h0, x1 - h1);
    }
    const s16x8 qh = qh_.v, ql = ql_.v;
    qn2 += __shfl_xor(qn2, 16);
    qn2 += __shfl_xor(qn2, 32);

    const int Tl = T & 255;
    const int sk = Tl >> 2, kc = Tl & 3;
    const int dv = Tl & 31, vc = Tl >> 5;
    const float* kbase = K + ((size_t)(b * NS * NH) + h) * 32;
    const float* vbase = V + ((size_t)(b * NS * NH) + h) * 32;
    const int kphys = (kc ^ swzK(sk)) * 8;
    const int vphys = (vc ^ swzV(dv)) * 8;

    int s0 = half * 1024;
    float4 ka = *(const float4*)(kbase + (size_t)(s0 + sk) * 256 + kc * 8);
    float4 kb = *(const float4*)(kbase + (size_t)(s0 + sk) * 256 + kc * 8 + 4);
    float vr[8];
#pragma unroll
    for (int i = 0; i < 8; i++) vr[i] = vbase[(size_t)(s0 + 8 * vc + i) * 256 + dv];

    f32x4 acc0 = {0.f, 0.f, 0.f, 0.f}, acc1 = {0.f, 0.f, 0.f, 0.f};
    float m = -INFINITY, l = 0.f;

    for (int t = 0; t < 16; ++t) {
        {
            float kx[8] = {ka.x, ka.y, ka.z, ka.w, kb.x, kb.y, kb.z, kb.w};
            unsigned hh[4], ll[4];
            float kn2p = 0.f;
#pragma unroll
            for (int i = 0; i < 4; i++) {
                float x0 = kx[2 * i], x1 = kx[2 * i + 1];
                kn2p = fmaf(x0, x0, kn2p);
                kn2p = fmaf(x1, x1, kn2p);
                unsigned h01 = pk2(x0, x1);
                hh[i] = h01;
                float h0 = __uint_as_float(h01 << 16);
                float h1 = __uint_as_float(h01 & 0xffff0000u);
                ll[i] = pk2(x0 - h0, x1 - h1);
            }
            *(uint4*)&u.s.Kh[half][sk][kphys] = make_uint4(hh[0], hh[1], hh[2], hh[3]);
            *(uint4*)&u.s.Kl[half][sk][kphys] = make_uint4(ll[0], ll[1], ll[2], ll[3]);
            kn2p = dpp_add<0xB1>(kn2p);
            kn2p = dpp_add<0x4E>(kn2p);
            if (kc == 0) u.s.kn2[half][sk] = kn2p;
            *(uint4*)&u.s.Vt[half][dv][vphys] =
                make_uint4(pk2(vr[0], vr[1]), pk2(vr[2], vr[3]),
                           pk2(vr[4], vr[5]), pk2(vr[6], vr[7]));
        }
        const int tn = (t + 1 < 16) ? t + 1 : t;
        const int sn = half * 1024 + tn * 64;
        ka = *(const float4*)(kbase + (size_t)(sn + sk) * 256 + kc * 8);
        kb = *(const float4*)(kbase + (size_t)(sn + sk) * 256 + kc * 8 + 4);
#pragma unroll
        for (int i = 0; i < 8; i++) vr[i] = vbase[(size_t)(sn + 8 * vc + i) * 256 + dv];

        __syncthreads();

        f32x4 d[4], kn2v[4];
        const f32x4 z = {0.f, 0.f, 0.f, 0.f};
        const int skr = swzK(lc);
#pragma unroll
        for (int st = 0; st < 4; st++) {
            kn2v[st] = *(f32x4*)&u.s.kn2[half][16 * st + 4 * g];
            s16x8 kh = *(s16x8*)&u.s.Kh[half][16 * st + lc][(g ^ skr) * 8];
            s16x8 kl = *(s16x8*)&u.s.Kl[half][16 * st + lc][(g ^ skr) * 8];
            f32x4 dd = __builtin_amdgcn_mfma_f32_16x16x32_bf16(kl, qh, z, 0, 0, 0);
            dd = __builtin_amdgcn_mfma_f32_16x16x32_bf16(kh, ql, dd, 0, 0, 0);
            dd = __builtin_amdgcn_mfma_f32_16x16x32_bf16(kh, qh, dd, 0, 0, 0);
            d[st] = dd;
        }

        float sc[4][4];
#pragma unroll
        for (int st = 0; st < 4; st++)
#pragma unroll
            for (int r = 0; r < 4; r++) {
                float dd = d[st][r];
                float w = fmaxf(fmaf(-dd, dd, qn2 * kn2v[st][r]), 0.f);
                sc[st][r] = (dd - w) * CSC;
            }

        float x0 = fmaxf(fmaxf(sc[0][0], sc[0][1]), fmaxf(sc[0][2], sc[0][3]));
        float x1 = fmaxf(fmaxf(sc[1][0], sc[1][1]), fmaxf(sc[1][2], sc[1][3]));
        float x2 = fmaxf(fmaxf(sc[2][0], sc[2][1]), fmaxf(sc[2][2], sc[2][3]));
        float x3 = fmaxf(fmaxf(sc[3][0], sc[3][1]), fmaxf(sc[3][2], sc[3][3]));
        float tm = fmaxf(fmaxf(x0, x1), fmaxf(x2, x3));
        tm = fmaxf(tm, __shfl_xor(tm, 16));
        tm = fmaxf(tm, __shfl_xor(tm, 32));
        const float nm = fmaxf(m, tm);
        const float al = __builtin_amdgcn_exp2f(m - nm);
        m = nm;
        float p[4][4], ls = 0.f;
#pragma unroll
        for (int st = 0; st < 4; st++)
#pragma unroll
            for (int r = 0; r < 4; r++) {
                p[st][r] = __builtin_amdgcn_exp2f(sc[st][r] - nm);
                ls += p[st][r];
            }
        l = fmaf(l, al, ls);
        acc0 *= al;
        acc1 *= al;

#pragma unroll
        for (int st = 0; st < 4; st++) {
            const int off = ((2 * st + (g >> 1)) ^ (lc & 7)) * 8 + (g & 1) * 4;
            *(uint2*)&sP[wave][lc][off] =
                make_uint2(pk2(p[st][0], p[st][1]), pk2(p[st][2], p[st][3]));
        }
        __builtin_amdgcn_s_waitcnt(0xC07F);

        const int svl = swzV(lc), svh = swzV(lc + 16), spl = lc & 7;
        s16x8 va00 = *(s16x8*)&u.s.Vt[half][lc][(g ^ svl) * 8];
        s16x8 va01 = *(s16x8*)&u.s.Vt[half][lc][((4 + g) ^ svl) * 8];
        s16x8 va10 = *(s16x8*)&u.s.Vt[half][lc + 16][(g ^ svh) * 8];
        s16x8 va11 = *(s16x8*)&u.s.Vt[half][lc + 16][((4 + g) ^ svh) * 8];
        s16x8 pb0 = *(s16x8*)&sP[wave][lc][(g ^ spl) * 8];
        s16x8 pb1 = *(s16x8*)&sP[wave][lc][((4 + g) ^ spl) * 8];
        acc0 = __builtin_amdgcn_mfma_f32_16x16x32_bf16(va00, pb0, acc0, 0, 0, 0);
        acc0 = __builtin_amdgcn_mfma_f32_16x16x32_bf16(va01, pb1, acc0, 0, 0, 0);
        acc1 = __builtin_amdgcn_mfma_f32_16x16x32_bf16(va10, pb0, acc1, 0, 0, 0);
        acc1 = __builtin_amdgcn_mfma_f32_16x16x32_bf16(va11, pb1, acc1, 0, 0, 0);

        __syncthreads();
    }

    l += __shfl_xor(l, 16);
    l += __shfl_xor(l, 32);
#pragma unroll
    for (int r = 0; r < 4; r++) {
        u.c.acc[wave][4 * g + r][lc] = acc0[r];
        u.c.acc[wave][16 + 4 * g + r][lc] = acc1[r];
    }
    if (lane < 16) {
        u.c.m[wave][lc] = m;
        u.c.l[wave][lc] = l;
    }
    __syncthreads();

    const int q = T >> 3, dq = (T & 7) * 4, qr = q & 15;
    const int w0 = q >> 4, w1 = w0 + 4;
    float m0 = u.c.m[w0][qr], m1 = u.c.m[w1][qr];
    float l0 = u.c.l[w0][qr], l1 = u.c.l[w1][qr];
    float mf = fmaxf(m0, m1);
    float e0 = __builtin_amdgcn_exp2f(m0 - mf);
    float e1 = __builtin_amdgcn_exp2f(m1 - mf);
    float inv = 1.f / fmaf(l1, e1, l0 * e0);
    e0 *= inv;
    e1 *= inv;
    float4 o;
    o.x = u.c.acc[w0][dq + 0][qr] * e0 + u.c.acc[w1][dq + 0][qr] * e1;
    o.y = u.c.acc[w0][dq + 1][qr] * e0 + u.c.acc[w1][dq + 1][qr] * e1;
    o.z = u.c.acc[w0][dq + 2][qr] * e0 + u.c.acc[w1][dq + 2][qr] * e1;
    o.w = u.c.acc[w0][dq + 3][qr] * e0 + u.c.acc[w1][dq + 3][qr] * e1;
    *(float4*)(O + ((size_t)((b * NL + qt * 64 + q) * NH + h)) * 32 + dq) = o;
}

extern "C" void kernel_launch(void* const* d_in, const int* in_sizes, int n_in,
                              void* d_out, int out_size, void* d_ws, size_t ws_size,
                              hipStream_t stream) {
    const float* Q = (const float*)d_in[0];
    const float* K = (const float*)d_in[1];
    const float* V = (const float*)d_in[2];
    float* O = (float*)d_out;

    if (ws_size >= (size_t)WS_NEED) {
        float* kn2w = (float*)((char*)d_ws + WS_KN2_OFF);
        u16* khkl = (u16*)((char*)d_ws + WS_KHKL_OFF);
        u16* vtw = (u16*)((char*)d_ws + WS_VT_OFF);
        float* pacc = (float*)((char*)d_ws + WS_PACC_OFF);
        float* pml = (float*)((char*)d_ws + WS_PML_OFF);
        ga_pre<<<NBH * 32, 256, 0, stream>>>(K, V, kn2w, khkl, vtw);
        // grid = 32 qt-blocks x 64 (bh,strip) groups = 2048 (matches qt=blk>>6)
        ga_lean<<<NBH * 32 * STRIPS, 256, 0, stream>>>(Q, kn2w, khkl, vtw, pacc, pml);
        ga_combine<<<(NBH * NL * 8) / 256, 256, 0, stream>>>(pacc, pml, O);
    } else {
        ga_fallback<<<NBH * 32, 512, 0, stream>>>(Q, K, V, O);
    }
}